// Round 1
// baseline (390.986 us; speedup 1.0000x reference)
//
#include <hip/hip_runtime.h>
#include <hip/hip_bf16.h>

// Problem constants
#define B_    32
#define C_    256
#define HW_   3136   // 56*56
#define OC_   256
#define M_    8
#define KPB_  589824 // per-sample wl shorts: 72 kblocks * 8192

typedef short v8s __attribute__((ext_vector_type(8)));   // 8 x bf16 (4 VGPRs)
typedef float f32x4 __attribute__((ext_vector_type(4)));

union bf8pack { v8s v; __hip_bfloat16 h[8]; };

__device__ __forceinline__ void gll16(const short* src, short* dst) {
    __builtin_amdgcn_global_load_lds((const __attribute__((address_space(1))) void*)src,
                                     (__attribute__((address_space(3))) void*)dst, 16, 0, 0);
}

// ---------------------------------------------------------------------------
// 0) zero the gap accumulator (ws is poisoned 0xAA before every launch)
__global__ void zero_gap_kernel(float* __restrict__ gap) {
    gap[blockIdx.x * 256 + threadIdx.x] = 0.f;
}

// ---------------------------------------------------------------------------
// 1) x (f32, BCHW) -> xg (bf16, [b][ib=8][p][32] channel-blocked), fused GAP.
//    Store phase emits 16B per thread (8 contiguous channels per pixel).
__global__ __launch_bounds__(256) void xcast_kernel(const float* __restrict__ x,
                                                    short* __restrict__ xg,
                                                    float* __restrict__ gap) {
    __shared__ __hip_bfloat16 tile[64][65];   // [channel][pixel], +1 pad
    int b = blockIdx.z, ct = blockIdx.y, pt = blockIdx.x;
    int p0 = pt*64, c0 = ct*64;
    int tp = threadIdx.x & 63, tc = threadIdx.x >> 6;
    const float* xb = x + ((size_t)b*C_ + c0) * HW_ + p0;
    #pragma unroll
    for (int j = 0; j < 16; ++j) {
        int cl = tc + j*4;
        float v = xb[(size_t)cl*HW_ + tp];
        tile[cl][tp] = __float2bfloat16(v);
        float s = v;
        #pragma unroll
        for (int off = 32; off; off >>= 1) s += __shfl_xor(s, off, 64);
        if (tp == 0) atomicAdd(&gap[b*C_ + c0 + cl], s);
    }
    __syncthreads();
    // 64 px * 8 chunks(8ch) = 512 v8s stores, 2 per thread
    #pragma unroll
    for (int it = 0; it < 2; ++it) {
        int idx = it*256 + threadIdx.x;
        int px = idx >> 3, ck = idx & 7;
        bf8pack pk;
        #pragma unroll
        for (int j = 0; j < 8; ++j) pk.h[j] = tile[ck*8 + j][px];
        int c = c0 + ck*8;
        size_t dst = (((size_t)b*8 + (c >> 5))*HW_ + p0 + px)*32 + (c & 31);
        *(v8s*)(xg + dst) = pk.v;
    }
}

// ---------------------------------------------------------------------------
// 2) Gate softmax + combined bias, fused. One wave per sample. gap holds SUMS.
__global__ void alpha_kernel(const float* __restrict__ gap,
                             const float* __restrict__ gate_w,
                             const float* __restrict__ gate_b,
                             const float* __restrict__ bias,
                             float* __restrict__ alpha,
                             float* __restrict__ biasc) {
    int b = blockIdx.x, lane = threadIdx.x;
    const float inv = 1.0f / HW_;
    float g0 = gap[b*C_ + lane]*inv,       g1 = gap[b*C_ + 64 + lane]*inv;
    float g2 = gap[b*C_ + 128 + lane]*inv, g3 = gap[b*C_ + 192 + lane]*inv;
    float logit[M_];
    #pragma unroll
    for (int m = 0; m < M_; ++m) {
        const float* w = gate_w + m*C_;
        float s = g0*w[lane] + g1*w[64+lane] + g2*w[128+lane] + g3*w[192+lane];
        for (int off = 32; off; off >>= 1) s += __shfl_xor(s, off, 64);
        logit[m] = s + gate_b[m];
    }
    float mx = logit[0];
    #pragma unroll
    for (int m = 1; m < M_; ++m) mx = fmaxf(mx, logit[m]);
    float den = 0.f, e[M_];
    #pragma unroll
    for (int m = 0; m < M_; ++m) { e[m] = __expf(logit[m] - mx); den += e[m]; }
    float am[M_];
    #pragma unroll
    for (int m = 0; m < M_; ++m) am[m] = e[m] / den;   // every lane has all alphas
    if (lane < M_) alpha[b*M_ + lane] = am[lane];
    #pragma unroll
    for (int r = 0; r < 4; ++r) {
        int o = r*64 + lane;
        float s = 0.f;
        #pragma unroll
        for (int m = 0; m < M_; ++m) s += am[m] * bias[m*OC_ + o];
        biasc[b*OC_ + o] = s;
    }
}

// ---------------------------------------------------------------------------
// 3) Combine expert kernels: wl[b][ib(8)][tap(9)][o(256)][i_in(32)] bf16.
//    Each thread: one 8-channel chunk, reads 64 expert floats once, emits all
//    32 samples as 16B stores.
__global__ __launch_bounds__(256) void combine_kernel(const float* __restrict__ weight,
                                                      const float* __restrict__ alpha,
                                                      short* __restrict__ wl) {
    __shared__ float as[B_*M_];
    as[threadIdx.x] = alpha[threadIdx.x];
    __syncthreads();
    int gc  = blockIdx.x*256 + threadIdx.x;   // [0, 73728)
    int i8  = gc & 3;
    int o   = (gc >> 2) & 255;
    int t2  = gc >> 10;
    int tap = t2 % 9;
    int ib  = t2 / 9;
    int base = o*2304 + (ib*32 + i8*8)*9 + tap;   // + j*9
    float wv[M_][8];
    #pragma unroll
    for (int m = 0; m < M_; ++m)
        #pragma unroll
        for (int j = 0; j < 8; ++j)
            wv[m][j] = weight[(size_t)m*589824 + base + j*9];
    for (int b = 0; b < B_; ++b) {
        bf8pack pk;
        #pragma unroll
        for (int j = 0; j < 8; ++j) {
            float s = 0.f;
            #pragma unroll
            for (int m = 0; m < M_; ++m) s += as[b*M_+m] * wv[m][j];
            pk.h[j] = __float2bfloat16(s);
        }
        *(v8s*)(wl + (size_t)b*KPB_ + (size_t)gc*8) = pk.v;
    }
}

// ---------------------------------------------------------------------------
// 4) Implicit-GEMM conv, MFMA bf16 16x16x32.
//    Block = 128o x 256p, 4 waves of 64o x 128p (acc 4x8).
//    NEW (T3+T4+T5+T1): counted-vmcnt pipeline. A triple-buffered (3x8KB),
//    staged 2 taps ahead; B (384-px halo, 24KB) double-buffered per ib.
//    Raw s_barrier + counted s_waitcnt vmcnt(N) keeps prefetch loads in
//    flight ACROSS barriers (never drained to 0 in the main loop).
//    LDS = 72 KB -> 2 blocks/CU (144 <= 160 KB).
__global__ __launch_bounds__(256, 2) void conv_kernel(const short* __restrict__ xg,
                                                      const short* __restrict__ wl,
                                                      const float* __restrict__ biasc,
                                                      float* __restrict__ out) {
    __shared__ short smem[36864];  // 72 KB: A0@0 A1@4096 A2@8192, B0@12288, B1@24576 (shorts)

    // T1: XCD-chunk swizzle. 832 blocks = 8 XCDs * 104 (bijective, 832%8==0).
    // Consecutive swz ids share the same sample b -> same-XCD L2 reuse of xg/wl.
    const int wg  = blockIdx.x;
    const int swz = (wg & 7) * 104 + (wg >> 3);
    const int b   = swz / 26;
    const int rm  = swz - b * 26;
    const int ot  = rm / 13;
    const int pt  = rm - ot * 13;

    const int tid = threadIdx.x;
    const int wave = tid >> 6, lane = tid & 63, q = lane >> 4, ln = lane & 15;
    const int o_half = wave >> 1, p_half = wave & 1;
    const int P0 = pt*256;

    const int DOFF[9] = {-57,-56,-55,-1,0,1,55,56,57};

    unsigned vmask[8]; int p_lane[8];
    #pragma unroll
    for (int c = 0; c < 8; ++c) {
        int p = P0 + p_half*128 + c*16 + ln;
        p_lane[c] = p;
        int h = p/56, w = p%56;
        unsigned m = 0;
        #pragma unroll
        for (int tap = 0; tap < 9; ++tap) {
            int h2 = h + tap/3 - 1, w2 = w + tap%3 - 1;
            if ((unsigned)h2 < 56u && (unsigned)w2 < 56u) m |= (1u << tap);
        }
        vmask[c] = m;
    }

    const short* wbase = wl + (size_t)b*KPB_ + ot*4096 + tid*8;
    const short* xbase = xg + (size_t)(b*8)*HW_*32;

    auto stageA = [&](int kidx, int buf) {             // 2 gll16 = 2 vmcnt events
        const short* src = wbase + (size_t)kidx*8192;
        gll16(src,        &smem[buf*4096 + tid*8]);
        gll16(src + 2048, &smem[buf*4096 + tid*8 + 2048]);
    };
    auto stageB = [&](int ib, int buf) {               // 6 gll16 = 6 vmcnt events
        const short* src = xbase + ((long)ib*HW_ + P0 - 64)*32 + tid*8;
        short* dst = &smem[12288 + buf*12288 + tid*8];
        #pragma unroll
        for (int r = 0; r < 6; ++r) gll16(src + r*2048, dst + r*2048);
    };

    f32x4 acc[4][8];
    #pragma unroll
    for (int r = 0; r < 4; ++r)
        #pragma unroll
        for (int c = 0; c < 8; ++c) acc[r][c] = (f32x4){0.f,0.f,0.f,0.f};

    // Prologue FIFO order: B0(6), A0(2), A1(2)  -> vmcnt(2) at k=0 covers B0+A0.
    stageB(0, 0);
    stageA(0, 0);
    stageA(1, 1);

    const int a_lane_off = (o_half*64 + ln)*32 + q*8;           // + r*512
    const int b_lane_off = 12288 + (64 + p_half*128 + ln)*32 + q*8; // + (ib&1)*12288 + c*512 + doff*32
    const v8s vzero = {};

    for (int ib = 0; ib < 8; ++ib) {
        const short* bbuf = &smem[(ib & 1)*12288 + b_lane_off];
        #pragma unroll
        for (int tap = 0; tap < 9; ++tap) {
            const int k = ib*9 + tap;

            // T4: counted waits. FIFO after A[k]: A[k+1] (2) always (k<71);
            // +B[ib+1] (6) when a B-stage was issued between A[k] and A[k+1]
            // (taps 1,2 with ib<7). Final tap drains.
            if (k == 71) {
                asm volatile("s_waitcnt vmcnt(0)" ::: "memory");
            } else if ((tap == 1 || tap == 2) && ib < 7) {
                asm volatile("s_waitcnt vmcnt(8)" ::: "memory");
            } else {
                asm volatile("s_waitcnt vmcnt(2)" ::: "memory");
            }
            __builtin_amdgcn_s_barrier();
            asm volatile("" ::: "memory");          // no LDS-read hoist above barrier
            __builtin_amdgcn_sched_barrier(0);

            // Issue next stages AFTER barrier: target buffers were last read at
            // tap k-1; all waves' ds_reads of them retired before this barrier.
            if (k + 2 < 72) stageA(k + 2, (tap + 2) % 3);   // (k+2)%3 == (tap+2)%3
            if (tap == 0 && ib < 7) stageB(ib + 1, (ib + 1) & 1);

            const short* am = &smem[(tap % 3)*4096 + a_lane_off];  // k%3 == tap%3
            v8s a[4];
            #pragma unroll
            for (int r = 0; r < 4; ++r) a[r] = *(const v8s*)(am + r*512);
            const short* bm = bbuf + DOFF[tap]*32;
            __builtin_amdgcn_s_setprio(1);           // T5: favor MFMA-issuing wave
            #pragma unroll
            for (int c = 0; c < 8; ++c) {
                v8s v = *(const v8s*)(bm + c*512);
                v8s bf = ((vmask[c] >> tap) & 1) ? v : vzero;
                #pragma unroll
                for (int r = 0; r < 4; ++r)
                    acc[r][c] = __builtin_amdgcn_mfma_f32_16x16x32_bf16(a[r], bf, acc[r][c], 0, 0, 0);
            }
            __builtin_amdgcn_s_setprio(0);
        }
    }

    // Epilogue: D[row=o][col=p], col=lane&15, row=quad*4+reg
    const int o_block = ot*128 + o_half*64;
    #pragma unroll
    for (int c = 0; c < 8; ++c) {
        int p = p_lane[c];
        if (p >= HW_) continue;
        float* op = out + (size_t)b * OC_ * HW_ + p;
        #pragma unroll
        for (int r = 0; r < 4; ++r) {
            int o0 = o_block + r*16 + q*4;
            #pragma unroll
            for (int reg = 0; reg < 4; ++reg) {
                int o = o0 + reg;
                op[(size_t)o * HW_] = acc[r][c][reg] + biasc[b*OC_ + o];
            }
        }
    }
}

// ---------------------------------------------------------------------------
extern "C" void kernel_launch(void* const* d_in, const int* in_sizes, int n_in,
                              void* d_out, int out_size, void* d_ws, size_t ws_size,
                              hipStream_t stream) {
    const float* x      = (const float*)d_in[0];
    const float* weight = (const float*)d_in[1];
    const float* bias   = (const float*)d_in[2];
    const float* gate_w = (const float*)d_in[3];
    const float* gate_b = (const float*)d_in[4];
    float* out = (float*)d_out;

    // Workspace layout (bytes):
    //   gap   @ 0       : 32,768
    //   biasc @ 32768   : 32,768
    //   alpha @ 65536   : 1,024
    //   (pad — absorbs conv's B-halo negative overrun, up to -4 KB)
    //   xg    @ 131072  : 32*8*3136*32*2 = 51,380,224
    //   wl    @ 51,511,296 : 32*589824*2 = 37,748,736 (absorbs B-halo tail overrun)
    char* ws = (char*)d_ws;
    float* gap   = (float*)(ws);
    float* biasc = (float*)(ws + 32768);
    float* alpha = (float*)(ws + 65536);
    short* xg    = (short*)(ws + 131072);
    short* wl    = (short*)(ws + 51511296);

    zero_gap_kernel<<<32, 256, 0, stream>>>(gap);
    xcast_kernel   <<<dim3(49, 4, 32), 256, 0, stream>>>(x, xg, gap);
    alpha_kernel   <<<32,  64, 0, stream>>>(gap, gate_w, gate_b, bias, alpha, biasc);
    combine_kernel <<<288, 256, 0, stream>>>(weight, alpha, wl);
    conv_kernel    <<<832, 256, 0, stream>>>(xg, wl, biasc, out);
}